// Round 7
// baseline (550.404 us; speedup 1.0000x reference)
//
#include <hip/hip_runtime.h>
#include <hip/hip_bf16.h>
#include <stdint.h>

#define DEVI __device__ __forceinline__

typedef short s16x8 __attribute__((ext_vector_type(8)));
typedef short s16x4 __attribute__((ext_vector_type(4)));
typedef float f32x4 __attribute__((ext_vector_type(4)));

static constexpr int BB = 32, SS = 1000, EE = 1024, AA = 512;
static constexpr int MM = BB * SS;  // 32000

// workspace layout (bytes)
static constexpr size_t OFF_X16 = 0;                                   // [M][E] bf16
static constexpr size_t OFF_Q   = OFF_X16 + (size_t)MM * EE * 2;       // [M][A] bf16 (pre-scaled by log2e/sqrt(S))
static constexpr size_t OFF_K   = OFF_Q  + (size_t)MM * AA * 2;        // [M][A] bf16
static constexpr size_t OFF_VT  = OFF_K  + (size_t)MM * AA * 2;       // [B][A][S] bf16
static constexpr size_t OFF_WT  = OFF_VT + (size_t)BB * AA * SS * 2;   // 3 x [A][E] bf16 (z=0:Wq 1:Wk 2:Wv)

DEVI unsigned short f2bf(float f) {  // round-to-nearest-even f32 -> bf16
  union { float f; unsigned int u; } c; c.f = f;
  unsigned int u = c.u + 0x7fffu + ((c.u >> 16) & 1u);
  return (unsigned short)(u >> 16);
}

DEVI void gl_lds16(const void* g, void* l) {  // async global->LDS, 16B/lane, linear dest
  __builtin_amdgcn_global_load_lds(
      (const __attribute__((address_space(1))) unsigned int*)g,
      (__attribute__((address_space(3))) unsigned int*)l, 16, 0, 0);
}

DEVI void wg_barrier() {
  asm volatile("" ::: "memory");
  __builtin_amdgcn_s_barrier();
  asm volatile("" ::: "memory");
}

DEVI float fast_exp2(float x) {
#if __has_builtin(__builtin_amdgcn_exp2f)
  return __builtin_amdgcn_exp2f(x);
#else
  return __builtin_exp2f(x);
#endif
}

// ---------------------------------------------------------------- prep kernels
__global__ __launch_bounds__(256) void x_to_bf16_kernel(const float* __restrict__ x,
                                                        unsigned short* __restrict__ x16) {
  const long n4 = (long)MM * EE / 4;
  long i = (long)blockIdx.x * blockDim.x + threadIdx.x;
  const long stride = (long)gridDim.x * blockDim.x;
  for (; i < n4; i += stride) {
    const float4 v = ((const float4*)x)[i];
    ushort4 o;
    o.x = f2bf(v.x); o.y = f2bf(v.y); o.z = f2bf(v.z); o.w = f2bf(v.w);
    ((ushort4*)x16)[i] = o;
  }
}

// transpose+convert W [E][A] f32 -> WT [A][E] bf16; grid (E/64, A/64, 3)
__global__ __launch_bounds__(256) void wt_kernel(const float* __restrict__ Wq,
                                                 const float* __restrict__ Wk,
                                                 const float* __restrict__ Wv,
                                                 unsigned short* __restrict__ WT) {
  const float* W = (blockIdx.z == 0) ? Wq : (blockIdx.z == 1) ? Wk : Wv;
  unsigned short* out = WT + (size_t)blockIdx.z * AA * EE;
  __shared__ unsigned short t[64][65];
  const int k0 = blockIdx.x * 64, n0 = blockIdx.y * 64;
  #pragma unroll
  for (int i = 0; i < 16; ++i) {
    int idx = i * 256 + threadIdx.x;
    int r = idx >> 6, c = idx & 63;              // r: k-local, c: n-local
    t[r][c] = f2bf(W[(size_t)(k0 + r) * AA + n0 + c]);
  }
  __syncthreads();
  #pragma unroll
  for (int i = 0; i < 16; ++i) {
    int idx = i * 256 + threadIdx.x;
    int r = idx >> 6, c = idx & 63;              // r: n-local, c: k-local
    out[(size_t)(n0 + r) * EE + k0 + c] = t[c][r];
  }
}

// ---------------------------------------------------------------- QKV projection
// C[m][n] = sum_k X16[m][k]*WT[z][n][k]  (NT GEMM), 128x128 tile, BK=64,
// 4 waves (2x2 of 64x64), double-buffered global_load_lds + counted vmcnt.
__global__ __launch_bounds__(256, 2) void proj_kernel(
    const unsigned short* __restrict__ X16, const unsigned short* __restrict__ WT,
    const float* __restrict__ bq, const float* __restrict__ bk, const float* __restrict__ bv,
    unsigned short* __restrict__ Qo, unsigned short* __restrict__ Ko,
    unsigned short* __restrict__ VTo) {
  constexpr int BK = 64, NKT = EE / BK;  // 16 K-steps
  __shared__ unsigned char lds[65536];   // 2x16KB A | 2x16KB B; reused by epilogue
  unsigned char* ldsA = lds;             // [buf][128 rows][128B]
  unsigned char* ldsB = lds + 32768;
  const int tid = threadIdx.x, lane = tid & 63, wave = tid >> 6;
  const int z = blockIdx.z;
  const int m0 = blockIdx.x * 128, n0 = blockIdx.y * 128;
  const unsigned short* Wz = WT + (size_t)z * AA * EE;

  f32x4 acc[4][4];
  #pragma unroll
  for (int i = 0; i < 4; ++i)
    #pragma unroll
    for (int j = 0; j < 4; ++j) acc[i][j] = f32x4{0.f, 0.f, 0.f, 0.f};

  auto stage = [&](int buf, int kt) {
    #pragma unroll
    for (int i = 0; i < 4; ++i) {
      int c = i * 256 + tid;                 // 1024 16B chunks (A-tile)
      int row = c >> 3;
      int cb = ((c & 7) * 16) ^ ((row & 7) << 4);   // pre-swizzled source column
      gl_lds16(X16 + (size_t)(m0 + row) * EE + kt * BK + (cb >> 1), ldsA + buf * 16384 + c * 16);
    }
    #pragma unroll
    for (int i = 0; i < 4; ++i) {
      int c = i * 256 + tid;
      int row = c >> 3;
      int cb = ((c & 7) * 16) ^ ((row & 7) << 4);
      gl_lds16(Wz + (size_t)(n0 + row) * EE + kt * BK + (cb >> 1), ldsB + buf * 16384 + c * 16);
    }
  };

  auto compute = [&](int buf) {
    #pragma unroll
    for (int kk = 0; kk < 2; ++kk) {
      s16x8 a[4], b[4];
      #pragma unroll
      for (int m = 0; m < 4; ++m) {
        int row = (wave >> 1) * 64 + m * 16 + (lane & 15);
        int cb = (kk * 64 + (lane >> 4) * 16) ^ ((row & 7) << 4);
        a[m] = *(const s16x8*)(ldsA + buf * 16384 + row * 128 + cb);
      }
      #pragma unroll
      for (int n = 0; n < 4; ++n) {
        int row = (wave & 1) * 64 + n * 16 + (lane & 15);
        int cb = (kk * 64 + (lane >> 4) * 16) ^ ((row & 7) << 4);
        b[n] = *(const s16x8*)(ldsB + buf * 16384 + row * 128 + cb);
      }
      #pragma unroll
      for (int m = 0; m < 4; ++m)
        #pragma unroll
        for (int n = 0; n < 4; ++n)
          acc[m][n] = __builtin_amdgcn_mfma_f32_16x16x32_bf16(a[m], b[n], acc[m][n], 0, 0, 0);
    }
  };

  stage(0, 0);
  for (int kt = 0; kt < NKT; ++kt) {
    const int cur = kt & 1;
    if (kt + 1 < NKT) {
      stage(cur ^ 1, kt + 1);
      asm volatile("s_waitcnt vmcnt(8)" ::: "memory");  // current tile done; prefetch stays in flight
    } else {
      asm volatile("s_waitcnt vmcnt(0)" ::: "memory");
    }
    wg_barrier();
    compute(cur);
    wg_barrier();
  }

  // ---- epilogue: bias (+scale for Q), bf16, coalesce via LDS [128][136] tile ----
  const float* bias = (z == 0) ? bq : (z == 1) ? bk : bv;
  const float scale = (z == 0) ? 0.04562280215f : 1.0f;  // log2(e)/sqrt(1000) folded into Q
  unsigned short* T = (unsigned short*)lds;              // 128*136*2 = 34816B
  const int rbase = (wave >> 1) * 64 + (lane >> 4) * 4;  // local row (m / s dim)
  const int cbase = (wave & 1) * 64 + (lane & 15);       // local col (n / a dim)
  float bvals[4];
  #pragma unroll
  for (int n = 0; n < 4; ++n) bvals[n] = bias[n0 + cbase + n * 16];
  #pragma unroll
  for (int m = 0; m < 4; ++m) {
    #pragma unroll
    for (int n = 0; n < 4; ++n) {
      const int cl = cbase + n * 16;
      #pragma unroll
      for (int j = 0; j < 4; ++j) {
        const int rl = rbase + m * 16 + j;
        const unsigned short h = f2bf((acc[m][n][j] + bvals[n]) * scale);
        if (z == 2) T[cl * 136 + rl] = h;   // transposed: [a_local][s_local]
        else        T[rl * 136 + cl] = h;   // natural:    [s_local][a_local]
      }
    }
  }
  wg_barrier();
  #pragma unroll
  for (int i = 0; i < 8; ++i) {
    int c2 = i * 256 + tid;                 // 2048 chunks of 16B
    int r = c2 >> 4, ch = (c2 & 15) * 8;
    s16x8 chunk = *(const s16x8*)&T[r * 136 + ch];
    if (z == 2) {
      // r = a_local, ch.. = s_local. 16B chunk never straddles a batch (8 | 1000).
      const int rowg0 = m0 + ch;
      const int bb2 = rowg0 / SS, ss2 = rowg0 - bb2 * SS;
      *(s16x8*)&VTo[(size_t)bb2 * AA * SS + (size_t)(n0 + r) * SS + ss2] = chunk;
    } else {
      unsigned short* O = (z == 0) ? Qo : Ko;
      *(s16x8*)&O[(size_t)(m0 + r) * AA + n0 + ch] = chunk;
    }
  }
}

// ---------------------------------------------------------------- fused causal attention
// grid 512 linear. b = L&31 (XCD pin: L%8 = b%8). Balanced pairing:
// tq = (L<256) ? 15-(L>>5) : (L-256)>>5  -> CU-mates have tq1+tq2=15 -> 34 tile-iters/CU.
// KVB=32 single LDS buffer (69KB -> 2 blocks/CU) + T14 reg-prefetch of tile t+1
// (issue global loads before compute, ds_write after post-PV barrier).
__global__ __launch_bounds__(256, 2) void attn_kernel(
    const unsigned short* __restrict__ Qs, const unsigned short* __restrict__ Ks,
    const unsigned short* __restrict__ VT, float* __restrict__ out) {
  constexpr int KVB = 32;
  __shared__ unsigned char ldsK[KVB * AA * 2];   // 32KB, XOR-swizzled rows
  __shared__ unsigned char ldsV[AA * KVB * 2];   // 32KB, pair-layout swizzled
  __shared__ unsigned char ldsP[4][16 * 80];     // per-wave P bounce, 5KB

  const int tid = threadIdx.x, lane = tid & 63, wave = tid >> 6;
  const int L = blockIdx.x;
  const int b  = L & 31;                                     // XCD = L%8 = b%8
  const int tq = (L < 256) ? (15 - (L >> 5)) : ((L - 256) >> 5);  // balanced pairs
  const int q0w = tq * 64 + wave * 16;

  // hoisted per-lane stage offsets (elements)
  const unsigned short* kbase = Ks + (size_t)b * SS * AA;
  const unsigned short* vbase = VT + (size_t)b * AA * SS;
  unsigned int koff[8], voff[8];
  #pragma unroll
  for (int i = 0; i < 8; ++i) {
    int c = i * 256 + tid;                   // 2048 chunks
    int r = c >> 6;                          // K row 0..31
    int cb = ((c & 63) * 16) ^ ((r & 7) << 4);
    koff[i] = r * AA + (cb >> 1);
    int pair = c >> 3;
    int within = (c & 7) * 16;
    int half = within >> 6;
    int kb = (within & 63) ^ ((pair & 3) << 4);
    int a_ = pair * 2 + half;
    voff[i] = a_ * SS + (kb >> 1);
  }

  // Q fragments in registers: 16 rows x 512 k
  s16x8 qf[16];
  {
    int qrow = q0w + (lane & 15);
    int qr = qrow < SS ? qrow : SS - 1;
    const unsigned short* qp = Qs + (size_t)(b * SS + qr) * AA + (lane >> 4) * 8;
    #pragma unroll
    for (int f = 0; f < 16; ++f) qf[f] = *(const s16x8*)(qp + f * 32);
  }

  f32x4 o[32];
  #pragma unroll
  for (int n = 0; n < 32; ++n) o[n] = f32x4{0.f, 0.f, 0.f, 0.f};
  float mrun[4], ps[4];
  #pragma unroll
  for (int j = 0; j < 4; ++j) { mrun[j] = -__builtin_inff(); ps[j] = 0.f; }

  const int kmax = (tq * 64 + 64 < SS) ? tq * 64 + 64 : SS;
  const int ntiles = (kmax + KVB - 1) / KVB;

  // ---- prologue: stage tile 0 direct to LDS ----
  #pragma unroll
  for (int i = 0; i < 8; ++i) gl_lds16(kbase + koff[i], ldsK + tid * 16 + i * 4096);
  #pragma unroll
  for (int i = 0; i < 8; ++i) gl_lds16(vbase + voff[i], ldsV + tid * 16 + i * 4096);
  asm volatile("s_waitcnt vmcnt(0)" ::: "memory");
  wg_barrier();

  for (int t = 0; t < ntiles; ++t) {
    const int k0 = t * KVB;
    const bool pf = (t + 1 < ntiles);

    // ---- T14: issue next-tile loads into registers (latency hides under compute) ----
    s16x8 kst[8], vst[8];
    if (pf) {
      #pragma unroll
      for (int i = 0; i < 8; ++i)
        kst[i] = *(const s16x8*)(kbase + koff[i] + (unsigned)((t + 1) * (KVB * AA)));
      #pragma unroll
      for (int i = 0; i < 8; ++i)
        vst[i] = *(const s16x8*)(vbase + voff[i] + (unsigned)((t + 1) * KVB));
    }

    // ---- QK^T: p[16 rows x 32 keys] ----
    f32x4 p0 = {0.f, 0.f, 0.f, 0.f}, p1 = {0.f, 0.f, 0.f, 0.f};
    {
      const int r0 = lane & 15;
      const int sw = (r0 & 7) << 4;
      const int kb16 = (lane >> 4) * 16;
      const int rb0 = r0 << 10, rb1 = (r0 + 16) << 10;
      #pragma unroll
      for (int f = 0; f < 16; ++f) {
        const int off = f * 64 + kb16;
        s16x8 kb0 = *(const s16x8*)&ldsK[rb0 + (off ^ sw)];
        s16x8 kb1 = *(const s16x8*)&ldsK[rb1 + (off ^ sw)];
        p0 = __builtin_amdgcn_mfma_f32_16x16x32_bf16(qf[f], kb0, p0, 0, 0, 0);
        p1 = __builtin_amdgcn_mfma_f32_16x16x32_bf16(qf[f], kb1, p1, 0, 0, 0);
      }
    }

    // ---- causal mask + defer-max online softmax ----
    const int kcol = k0 + (lane & 15);
    float lm[4];
    #pragma unroll
    for (int j = 0; j < 4; ++j) {
      const int q = q0w + (lane >> 4) * 4 + j;
      float s0 = p0[j], s1 = p1[j];
      if (kcol > q || kcol >= SS) s0 = -__builtin_inff();
      if (kcol + 16 > q || kcol + 16 >= SS) s1 = -__builtin_inff();
      p0[j] = s0; p1[j] = s1;
      lm[j] = fmaxf(s0, s1);
    }
    const int myneed = (lm[0] > mrun[0] + 8.f) | (lm[1] > mrun[1] + 8.f) |
                       (lm[2] > mrun[2] + 8.f) | (lm[3] > mrun[3] + 8.f);
    if (__any(myneed)) {                        // rare after tile 0
      float rm[4] = {lm[0], lm[1], lm[2], lm[3]};
      #pragma unroll
      for (int st = 1; st <= 8; st <<= 1)
        #pragma unroll
        for (int j = 0; j < 4; ++j) rm[j] = fmaxf(rm[j], __shfl_xor(rm[j], st));
      float corr[4];
      #pragma unroll
      for (int j = 0; j < 4; ++j) {
        const float mnew = fmaxf(mrun[j], rm[j]);
        corr[j] = fast_exp2(mrun[j] - mnew);    // exp2(-inf)=0 on first tile
        mrun[j] = mnew;
        ps[j] *= corr[j];
      }
      #pragma unroll
      for (int n = 0; n < 32; ++n)
        #pragma unroll
        for (int j = 0; j < 4; ++j) o[n][j] *= corr[j];
    }
    #pragma unroll
    for (int j = 0; j < 4; ++j) {               // P = exp2(s - m); per-lane partial sums
      const float e0 = fast_exp2(p0[j] - mrun[j]);
      const float e1 = fast_exp2(p1[j] - mrun[j]);
      ps[j] += e0 + e1;
      p0[j] = e0; p1[j] = e1;
    }

    // ---- P (C-layout) -> bf16 -> wave-private LDS -> A-fragment ----
    {
      unsigned short* pb = (unsigned short*)&ldsP[wave][0];
      const int prow = (lane >> 4) * 4, pc = lane & 15;
      #pragma unroll
      for (int j = 0; j < 4; ++j) {
        pb[(prow + j) * 40 + pc]      = f2bf(p0[j]);
        pb[(prow + j) * 40 + pc + 16] = f2bf(p1[j]);
      }
    }
    s16x8 pa;
    {
      const unsigned char* pp = &ldsP[wave][(lane & 15) * 80 + (lane >> 4) * 16];
      s16x4 lo = *(const s16x4*)pp;
      s16x4 hi = *(const s16x4*)(pp + 8);
      pa = s16x8{lo[0], lo[1], lo[2], lo[3], hi[0], hi[1], hi[2], hi[3]};
    }

    // ---- PV: o[q][a] += P[q][k] * VT[a][k] ----
    #pragma unroll
    for (int n = 0; n < 32; ++n) {
      const int a_ = n * 16 + (lane & 15);
      const int pair = a_ >> 1;
      const int off = pair * 128 + (a_ & 1) * 64 + (((lane >> 4) * 16) ^ ((pair & 3) << 4));
      s16x8 vb = *(const s16x8*)&ldsV[off];
      o[n] = __builtin_amdgcn_mfma_f32_16x16x32_bf16(pa, vb, o[n], 0, 0, 0);
    }

    wg_barrier();                    // all LDS reads of tile t complete
    if (pf) {                        // write prefetched tile t+1 (compiler waits vmcnt)
      #pragma unroll
      for (int i = 0; i < 8; ++i) *(s16x8*)(ldsK + tid * 16 + i * 4096) = kst[i];
      #pragma unroll
      for (int i = 0; i < 8; ++i) *(s16x8*)(ldsV + tid * 16 + i * 4096) = vst[i];
    }
    wg_barrier();                    // writes visible before next iteration reads
  }

  // ---- finalize: reduce per-lane partial sums, divide, store fp32 ----
  #pragma unroll
  for (int st = 1; st <= 8; st <<= 1)
    #pragma unroll
    for (int j = 0; j < 4; ++j) ps[j] += __shfl_xor(ps[j], st);
  #pragma unroll
  for (int j = 0; j < 4; ++j) {
    const int q = q0w + (lane >> 4) * 4 + j;
    if (q < SS) {
      const float inv = 1.0f / ps[j];
      float* op = out + (size_t)(b * SS + q) * AA + (lane & 15);
      #pragma unroll
      for (int n = 0; n < 32; ++n) op[n * 16] = o[n][j] * inv;
    }
  }
}

// ---------------------------------------------------------------- launch
extern "C" void kernel_launch(void* const* d_in, const int* in_sizes, int n_in,
                              void* d_out, int out_size, void* d_ws, size_t ws_size,
                              hipStream_t stream) {
  const float* x  = (const float*)d_in[0];
  const float* Wk = (const float*)d_in[1];
  const float* bk = (const float*)d_in[2];
  const float* Wq = (const float*)d_in[3];
  const float* bq = (const float*)d_in[4];
  const float* Wv = (const float*)d_in[5];
  const float* bv = (const float*)d_in[6];

  char* ws = (char*)d_ws;
  unsigned short* X16 = (unsigned short*)(ws + OFF_X16);
  unsigned short* Qw  = (unsigned short*)(ws + OFF_Q);
  unsigned short* Kw  = (unsigned short*)(ws + OFF_K);
  unsigned short* VTw = (unsigned short*)(ws + OFF_VT);
  unsigned short* WT  = (unsigned short*)(ws + OFF_WT);

  x_to_bf16_kernel<<<dim3(2048), dim3(256), 0, stream>>>(x, X16);
  wt_kernel<<<dim3(EE / 64, AA / 64, 3), dim3(256), 0, stream>>>(Wq, Wk, Wv, WT);
  proj_kernel<<<dim3(MM / 128, AA / 128, 3), dim3(256), 0, stream>>>(
      X16, WT, bq, bk, bv, Qw, Kw, VTw);
  attn_kernel<<<dim3(512), dim3(256), 0, stream>>>(Qw, Kw, VTw, (float*)d_out);
}

// Round 8
// 380.990 us; speedup vs baseline: 1.4447x; 1.4447x over previous
//
#include <hip/hip_runtime.h>
#include <hip/hip_bf16.h>
#include <stdint.h>

#define DEVI __device__ __forceinline__

typedef short s16x8 __attribute__((ext_vector_type(8)));
typedef short s16x4 __attribute__((ext_vector_type(4)));
typedef float f32x4 __attribute__((ext_vector_type(4)));

static constexpr int BB = 32, SS = 1000, EE = 1024, AA = 512;
static constexpr int MM = BB * SS;  // 32000

// workspace layout (bytes)
static constexpr size_t OFF_X16 = 0;                                   // [M][E] bf16
static constexpr size_t OFF_Q   = OFF_X16 + (size_t)MM * EE * 2;       // [M][A] bf16 (pre-scaled by log2e/sqrt(S))
static constexpr size_t OFF_K   = OFF_Q  + (size_t)MM * AA * 2;        // [M][A] bf16
static constexpr size_t OFF_VT  = OFF_K  + (size_t)MM * AA * 2;       // [B][A][S] bf16
static constexpr size_t OFF_WT  = OFF_VT + (size_t)BB * AA * SS * 2;   // 3 x [A][E] bf16 (z=0:Wq 1:Wk 2:Wv)

DEVI unsigned short f2bf(float f) {  // round-to-nearest-even f32 -> bf16
  union { float f; unsigned int u; } c; c.f = f;
  unsigned int u = c.u + 0x7fffu + ((c.u >> 16) & 1u);
  return (unsigned short)(u >> 16);
}

DEVI void gl_lds16(const void* g, void* l) {  // async global->LDS, 16B/lane, linear dest
  __builtin_amdgcn_global_load_lds(
      (const __attribute__((address_space(1))) unsigned int*)g,
      (__attribute__((address_space(3))) unsigned int*)l, 16, 0, 0);
}

DEVI void wg_barrier() {
  asm volatile("" ::: "memory");
  __builtin_amdgcn_s_barrier();
  asm volatile("" ::: "memory");
}

DEVI float fast_exp2(float x) {
#if __has_builtin(__builtin_amdgcn_exp2f)
  return __builtin_amdgcn_exp2f(x);
#else
  return __builtin_exp2f(x);
#endif
}

// ---------------------------------------------------------------- prep kernels
__global__ __launch_bounds__(256) void x_to_bf16_kernel(const float* __restrict__ x,
                                                        unsigned short* __restrict__ x16) {
  const long n4 = (long)MM * EE / 4;
  long i = (long)blockIdx.x * blockDim.x + threadIdx.x;
  const long stride = (long)gridDim.x * blockDim.x;
  for (; i < n4; i += stride) {
    const float4 v = ((const float4*)x)[i];
    ushort4 o;
    o.x = f2bf(v.x); o.y = f2bf(v.y); o.z = f2bf(v.z); o.w = f2bf(v.w);
    ((ushort4*)x16)[i] = o;
  }
}

// transpose+convert W [E][A] f32 -> WT [A][E] bf16; grid (E/64, A/64, 3)
__global__ __launch_bounds__(256) void wt_kernel(const float* __restrict__ Wq,
                                                 const float* __restrict__ Wk,
                                                 const float* __restrict__ Wv,
                                                 unsigned short* __restrict__ WT) {
  const float* W = (blockIdx.z == 0) ? Wq : (blockIdx.z == 1) ? Wk : Wv;
  unsigned short* out = WT + (size_t)blockIdx.z * AA * EE;
  __shared__ unsigned short t[64][65];
  const int k0 = blockIdx.x * 64, n0 = blockIdx.y * 64;
  #pragma unroll
  for (int i = 0; i < 16; ++i) {
    int idx = i * 256 + threadIdx.x;
    int r = idx >> 6, c = idx & 63;              // r: k-local, c: n-local
    t[r][c] = f2bf(W[(size_t)(k0 + r) * AA + n0 + c]);
  }
  __syncthreads();
  #pragma unroll
  for (int i = 0; i < 16; ++i) {
    int idx = i * 256 + threadIdx.x;
    int r = idx >> 6, c = idx & 63;              // r: n-local, c: k-local
    out[(size_t)(n0 + r) * EE + k0 + c] = t[c][r];
  }
}

// ---------------------------------------------------------------- QKV projection
// C[m][n] = sum_k X16[m][k]*WT[z][n][k]  (NT GEMM), 128x128 tile, BK=64,
// 4 waves (2x2 of 64x64), double-buffered global_load_lds + counted vmcnt.
__global__ __launch_bounds__(256, 2) void proj_kernel(
    const unsigned short* __restrict__ X16, const unsigned short* __restrict__ WT,
    const float* __restrict__ bq, const float* __restrict__ bk, const float* __restrict__ bv,
    unsigned short* __restrict__ Qo, unsigned short* __restrict__ Ko,
    unsigned short* __restrict__ VTo) {
  constexpr int BK = 64, NKT = EE / BK;  // 16 K-steps
  __shared__ unsigned char lds[65536];   // 2x16KB A | 2x16KB B; reused by epilogue
  unsigned char* ldsA = lds;             // [buf][128 rows][128B]
  unsigned char* ldsB = lds + 32768;
  const int tid = threadIdx.x, lane = tid & 63, wave = tid >> 6;
  const int z = blockIdx.z;
  const int m0 = blockIdx.x * 128, n0 = blockIdx.y * 128;
  const unsigned short* Wz = WT + (size_t)z * AA * EE;

  f32x4 acc[4][4];
  #pragma unroll
  for (int i = 0; i < 4; ++i)
    #pragma unroll
    for (int j = 0; j < 4; ++j) acc[i][j] = f32x4{0.f, 0.f, 0.f, 0.f};

  auto stage = [&](int buf, int kt) {
    #pragma unroll
    for (int i = 0; i < 4; ++i) {
      int c = i * 256 + tid;                 // 1024 16B chunks (A-tile)
      int row = c >> 3;
      int cb = ((c & 7) * 16) ^ ((row & 7) << 4);   // pre-swizzled source column
      gl_lds16(X16 + (size_t)(m0 + row) * EE + kt * BK + (cb >> 1), ldsA + buf * 16384 + c * 16);
    }
    #pragma unroll
    for (int i = 0; i < 4; ++i) {
      int c = i * 256 + tid;
      int row = c >> 3;
      int cb = ((c & 7) * 16) ^ ((row & 7) << 4);
      gl_lds16(Wz + (size_t)(n0 + row) * EE + kt * BK + (cb >> 1), ldsB + buf * 16384 + c * 16);
    }
  };

  auto compute = [&](int buf) {
    #pragma unroll
    for (int kk = 0; kk < 2; ++kk) {
      s16x8 a[4], b[4];
      #pragma unroll
      for (int m = 0; m < 4; ++m) {
        int row = (wave >> 1) * 64 + m * 16 + (lane & 15);
        int cb = (kk * 64 + (lane >> 4) * 16) ^ ((row & 7) << 4);
        a[m] = *(const s16x8*)(ldsA + buf * 16384 + row * 128 + cb);
      }
      #pragma unroll
      for (int n = 0; n < 4; ++n) {
        int row = (wave & 1) * 64 + n * 16 + (lane & 15);
        int cb = (kk * 64 + (lane >> 4) * 16) ^ ((row & 7) << 4);
        b[n] = *(const s16x8*)(ldsB + buf * 16384 + row * 128 + cb);
      }
      __builtin_amdgcn_s_setprio(1);
      #pragma unroll
      for (int m = 0; m < 4; ++m)
        #pragma unroll
        for (int n = 0; n < 4; ++n)
          acc[m][n] = __builtin_amdgcn_mfma_f32_16x16x32_bf16(a[m], b[n], acc[m][n], 0, 0, 0);
      __builtin_amdgcn_s_setprio(0);
    }
  };

  stage(0, 0);
  for (int kt = 0; kt < NKT; ++kt) {
    const int cur = kt & 1;
    if (kt + 1 < NKT) {
      stage(cur ^ 1, kt + 1);
      asm volatile("s_waitcnt vmcnt(8)" ::: "memory");  // current tile done; prefetch stays in flight
    } else {
      asm volatile("s_waitcnt vmcnt(0)" ::: "memory");
    }
    wg_barrier();
    compute(cur);
    wg_barrier();
  }

  // ---- epilogue: bias (+scale for Q), bf16, coalesce via LDS [128][136] tile ----
  const float* bias = (z == 0) ? bq : (z == 1) ? bk : bv;
  const float scale = (z == 0) ? 0.04562280215f : 1.0f;  // log2(e)/sqrt(1000) folded into Q
  unsigned short* T = (unsigned short*)lds;              // 128*136*2 = 34816B
  const int rbase = (wave >> 1) * 64 + (lane >> 4) * 4;  // local row (m / s dim)
  const int cbase = (wave & 1) * 64 + (lane & 15);       // local col (n / a dim)
  float bvals[4];
  #pragma unroll
  for (int n = 0; n < 4; ++n) bvals[n] = bias[n0 + cbase + n * 16];
  #pragma unroll
  for (int m = 0; m < 4; ++m) {
    #pragma unroll
    for (int n = 0; n < 4; ++n) {
      const int cl = cbase + n * 16;
      #pragma unroll
      for (int j = 0; j < 4; ++j) {
        const int rl = rbase + m * 16 + j;
        const unsigned short h = f2bf((acc[m][n][j] + bvals[n]) * scale);
        if (z == 2) T[cl * 136 + rl] = h;   // transposed: [a_local][s_local]
        else        T[rl * 136 + cl] = h;   // natural:    [s_local][a_local]
      }
    }
  }
  wg_barrier();
  #pragma unroll
  for (int i = 0; i < 8; ++i) {
    int c2 = i * 256 + tid;                 // 2048 chunks of 16B
    int r = c2 >> 4, ch = (c2 & 15) * 8;
    s16x8 chunk = *(const s16x8*)&T[r * 136 + ch];
    if (z == 2) {
      // r = a_local, ch.. = s_local. 16B chunk never straddles a batch (8 | 1000).
      const int rowg0 = m0 + ch;
      const int bb2 = rowg0 / SS, ss2 = rowg0 - bb2 * SS;
      *(s16x8*)&VTo[(size_t)bb2 * AA * SS + (size_t)(n0 + r) * SS + ss2] = chunk;
    } else {
      unsigned short* O = (z == 0) ? Qo : Ko;
      *(s16x8*)&O[(size_t)(m0 + r) * AA + n0 + ch] = chunk;
    }
  }
}

// ---------------------------------------------------------------- fused causal attention
// grid 512 linear. b = L&31 (XCD pin: L%8 = b%8). Balanced pairing:
// tq = (L<256) ? 15-(L>>5) : (L-256)>>5  -> CU-mates have tq1+tq2=15 -> 34 tile-iters/CU.
// KVB=32 single LDS buffer (69KB -> 2 blocks/CU). NO reg-prefetch (R7: spilled to scratch).
// QK^T split into 4 independent 8-deep MFMA chains; setprio around MFMA clusters.
__global__ __launch_bounds__(256, 2) void attn_kernel(
    const unsigned short* __restrict__ Qs, const unsigned short* __restrict__ Ks,
    const unsigned short* __restrict__ VT, float* __restrict__ out) {
  constexpr int KVB = 32;
  __shared__ unsigned char ldsK[KVB * AA * 2];   // 32KB, XOR-swizzled rows
  __shared__ unsigned char ldsV[AA * KVB * 2];   // 32KB, pair-layout swizzled
  __shared__ unsigned char ldsP[4][16 * 80];     // per-wave P bounce, 5KB

  const int tid = threadIdx.x, lane = tid & 63, wave = tid >> 6;
  const int L = blockIdx.x;
  const int b  = L & 31;                                          // XCD = L%8 = b%8
  const int tq = (L < 256) ? (15 - (L >> 5)) : ((L - 256) >> 5);  // balanced pairs
  const int q0w = tq * 64 + wave * 16;

  // hoisted per-lane stage offsets (elements)
  const unsigned short* kbase = Ks + (size_t)b * SS * AA;
  const unsigned short* vbase = VT + (size_t)b * AA * SS;
  unsigned int koff[8], voff[8];
  #pragma unroll
  for (int i = 0; i < 8; ++i) {
    int c = i * 256 + tid;                   // 2048 chunks
    int r = c >> 6;                          // K row 0..31
    int cb = ((c & 63) * 16) ^ ((r & 7) << 4);
    koff[i] = r * AA + (cb >> 1);
    int pair = c >> 3;
    int within = (c & 7) * 16;
    int half = within >> 6;
    int kb = (within & 63) ^ ((pair & 3) << 4);
    int a_ = pair * 2 + half;
    voff[i] = a_ * SS + (kb >> 1);
  }

  // Q fragments in registers: 16 rows x 512 k
  s16x8 qf[16];
  {
    int qrow = q0w + (lane & 15);
    int qr = qrow < SS ? qrow : SS - 1;
    const unsigned short* qp = Qs + (size_t)(b * SS + qr) * AA + (lane >> 4) * 8;
    #pragma unroll
    for (int f = 0; f < 16; ++f) qf[f] = *(const s16x8*)(qp + f * 32);
  }

  f32x4 o[32];
  #pragma unroll
  for (int n = 0; n < 32; ++n) o[n] = f32x4{0.f, 0.f, 0.f, 0.f};
  float mrun[4], ps[4];
  #pragma unroll
  for (int j = 0; j < 4; ++j) { mrun[j] = -__builtin_inff(); ps[j] = 0.f; }

  const int kmax = (tq * 64 + 64 < SS) ? tq * 64 + 64 : SS;
  const int ntiles = (kmax + KVB - 1) / KVB;

  for (int t = 0; t < ntiles; ++t) {
    const int k0 = t * KVB;
    // ---- stage K/V tile t (single buffer; previous tile fully consumed) ----
    #pragma unroll
    for (int i = 0; i < 8; ++i)
      gl_lds16(kbase + koff[i] + (unsigned)(t * (KVB * AA)), ldsK + tid * 16 + i * 4096);
    #pragma unroll
    for (int i = 0; i < 8; ++i)
      gl_lds16(vbase + voff[i] + (unsigned)(t * KVB), ldsV + tid * 16 + i * 4096);
    asm volatile("s_waitcnt vmcnt(0)" ::: "memory");
    wg_barrier();

    // ---- QK^T: p[16 rows x 32 keys], 4 independent 8-deep MFMA chains ----
    f32x4 p0a = {0.f, 0.f, 0.f, 0.f}, p0b = {0.f, 0.f, 0.f, 0.f};
    f32x4 p1a = {0.f, 0.f, 0.f, 0.f}, p1b = {0.f, 0.f, 0.f, 0.f};
    {
      const int r0 = lane & 15;
      const int sw = (r0 & 7) << 4;
      const int kb16 = (lane >> 4) * 16;
      const int rb0 = r0 << 10, rb1 = (r0 + 16) << 10;
      __builtin_amdgcn_s_setprio(1);
      #pragma unroll
      for (int f = 0; f < 8; ++f) {
        const int offA = f * 64 + kb16;
        const int offB = (f + 8) * 64 + kb16;
        s16x8 k0A = *(const s16x8*)&ldsK[rb0 + (offA ^ sw)];
        s16x8 k1A = *(const s16x8*)&ldsK[rb1 + (offA ^ sw)];
        s16x8 k0B = *(const s16x8*)&ldsK[rb0 + (offB ^ sw)];
        s16x8 k1B = *(const s16x8*)&ldsK[rb1 + (offB ^ sw)];
        p0a = __builtin_amdgcn_mfma_f32_16x16x32_bf16(qf[f], k0A, p0a, 0, 0, 0);
        p1a = __builtin_amdgcn_mfma_f32_16x16x32_bf16(qf[f], k1A, p1a, 0, 0, 0);
        p0b = __builtin_amdgcn_mfma_f32_16x16x32_bf16(qf[f + 8], k0B, p0b, 0, 0, 0);
        p1b = __builtin_amdgcn_mfma_f32_16x16x32_bf16(qf[f + 8], k1B, p1b, 0, 0, 0);
      }
      __builtin_amdgcn_s_setprio(0);
    }
    f32x4 p0 = p0a + p0b, p1 = p1a + p1b;

    // ---- causal mask + defer-max online softmax ----
    const int kcol = k0 + (lane & 15);
    float lm[4];
    #pragma unroll
    for (int j = 0; j < 4; ++j) {
      const int q = q0w + (lane >> 4) * 4 + j;
      float s0 = p0[j], s1 = p1[j];
      if (kcol > q || kcol >= SS) s0 = -__builtin_inff();
      if (kcol + 16 > q || kcol + 16 >= SS) s1 = -__builtin_inff();
      p0[j] = s0; p1[j] = s1;
      lm[j] = fmaxf(s0, s1);
    }
    const int myneed = (lm[0] > mrun[0] + 8.f) | (lm[1] > mrun[1] + 8.f) |
                       (lm[2] > mrun[2] + 8.f) | (lm[3] > mrun[3] + 8.f);
    if (__any(myneed)) {                        // rare after tile 0
      float rm[4] = {lm[0], lm[1], lm[2], lm[3]};
      #pragma unroll
      for (int st = 1; st <= 8; st <<= 1)
        #pragma unroll
        for (int j = 0; j < 4; ++j) rm[j] = fmaxf(rm[j], __shfl_xor(rm[j], st));
      float corr[4];
      #pragma unroll
      for (int j = 0; j < 4; ++j) {
        const float mnew = fmaxf(mrun[j], rm[j]);
        corr[j] = fast_exp2(mrun[j] - mnew);    // exp2(-inf)=0 on first tile
        mrun[j] = mnew;
        ps[j] *= corr[j];
      }
      #pragma unroll
      for (int n = 0; n < 32; ++n)
        #pragma unroll
        for (int j = 0; j < 4; ++j) o[n][j] *= corr[j];
    }
    #pragma unroll
    for (int j = 0; j < 4; ++j) {               // P = exp2(s - m); per-lane partial sums
      const float e0 = fast_exp2(p0[j] - mrun[j]);
      const float e1 = fast_exp2(p1[j] - mrun[j]);
      ps[j] += e0 + e1;
      p0[j] = e0; p1[j] = e1;
    }

    // ---- P (C-layout) -> bf16 -> wave-private LDS -> A-fragment ----
    {
      unsigned short* pb = (unsigned short*)&ldsP[wave][0];
      const int prow = (lane >> 4) * 4, pc = lane & 15;
      #pragma unroll
      for (int j = 0; j < 4; ++j) {
        pb[(prow + j) * 40 + pc]      = f2bf(p0[j]);
        pb[(prow + j) * 40 + pc + 16] = f2bf(p1[j]);
      }
    }
    s16x8 pa;
    {
      const unsigned char* pp = &ldsP[wave][(lane & 15) * 80 + (lane >> 4) * 16];
      s16x4 lo = *(const s16x4*)pp;
      s16x4 hi = *(const s16x4*)(pp + 8);
      pa = s16x8{lo[0], lo[1], lo[2], lo[3], hi[0], hi[1], hi[2], hi[3]};
    }

    // ---- PV: o[q][a] += P[q][k] * VT[a][k] ----
    __builtin_amdgcn_s_setprio(1);
    #pragma unroll
    for (int n = 0; n < 32; ++n) {
      const int a_ = n * 16 + (lane & 15);
      const int pair = a_ >> 1;
      const int off = pair * 128 + (a_ & 1) * 64 + (((lane >> 4) * 16) ^ ((pair & 3) << 4));
      s16x8 vb = *(const s16x8*)&ldsV[off];
      o[n] = __builtin_amdgcn_mfma_f32_16x16x32_bf16(pa, vb, o[n], 0, 0, 0);
    }
    __builtin_amdgcn_s_setprio(0);
    wg_barrier();  // all reads done before next stage overwrites
  }

  // ---- finalize: reduce per-lane partial sums, divide, store fp32 ----
  #pragma unroll
  for (int st = 1; st <= 8; st <<= 1)
    #pragma unroll
    for (int j = 0; j < 4; ++j) ps[j] += __shfl_xor(ps[j], st);
  #pragma unroll
  for (int j = 0; j < 4; ++j) {
    const int q = q0w + (lane >> 4) * 4 + j;
    if (q < SS) {
      const float inv = 1.0f / ps[j];
      float* op = out + (size_t)(b * SS + q) * AA + (lane & 15);
      #pragma unroll
      for (int n = 0; n < 32; ++n) op[n * 16] = o[n][j] * inv;
    }
  }
}

// ---------------------------------------------------------------- launch
extern "C" void kernel_launch(void* const* d_in, const int* in_sizes, int n_in,
                              void* d_out, int out_size, void* d_ws, size_t ws_size,
                              hipStream_t stream) {
  const float* x  = (const float*)d_in[0];
  const float* Wk = (const float*)d_in[1];
  const float* bk = (const float*)d_in[2];
  const float* Wq = (const float*)d_in[3];
  const float* bq = (const float*)d_in[4];
  const float* Wv = (const float*)d_in[5];
  const float* bv = (const float*)d_in[6];

  char* ws = (char*)d_ws;
  unsigned short* X16 = (unsigned short*)(ws + OFF_X16);
  unsigned short* Qw  = (unsigned short*)(ws + OFF_Q);
  unsigned short* Kw  = (unsigned short*)(ws + OFF_K);
  unsigned short* VTw = (unsigned short*)(ws + OFF_VT);
  unsigned short* WT  = (unsigned short*)(ws + OFF_WT);

  x_to_bf16_kernel<<<dim3(2048), dim3(256), 0, stream>>>(x, X16);
  wt_kernel<<<dim3(EE / 64, AA / 64, 3), dim3(256), 0, stream>>>(Wq, Wk, Wv, WT);
  proj_kernel<<<dim3(MM / 128, AA / 128, 3), dim3(256), 0, stream>>>(
      X16, WT, bq, bk, bv, Qw, Kw, VTw);
  attn_kernel<<<dim3(512), dim3(256), 0, stream>>>(Qw, Kw, VTw, (float*)d_out);
}

// Round 10
// 334.267 us; speedup vs baseline: 1.6466x; 1.1398x over previous
//
#include <hip/hip_runtime.h>
#include <hip/hip_bf16.h>
#include <stdint.h>

#define DEVI __device__ __forceinline__

typedef short s16x8 __attribute__((ext_vector_type(8)));
typedef short s16x4 __attribute__((ext_vector_type(4)));
typedef float f32x4 __attribute__((ext_vector_type(4)));

static constexpr int BB = 32, SS = 1000, EE = 1024, AA = 512;
static constexpr int MM = BB * SS;  // 32000

// workspace layout (bytes)
static constexpr size_t OFF_X16 = 0;                                   // [M][E] bf16
static constexpr size_t OFF_Q   = OFF_X16 + (size_t)MM * EE * 2;       // [M][A] bf16 (pre-scaled by log2e/sqrt(S))
static constexpr size_t OFF_K   = OFF_Q  + (size_t)MM * AA * 2;        // [M][A] bf16
static constexpr size_t OFF_VT  = OFF_K  + (size_t)MM * AA * 2;       // [B][A][S] bf16
static constexpr size_t OFF_WT  = OFF_VT + (size_t)BB * AA * SS * 2;   // 3 x [A][E] bf16 (z=0:Wq 1:Wk 2:Wv)

DEVI unsigned short f2bf(float f) {  // round-to-nearest-even f32 -> bf16
  union { float f; unsigned int u; } c; c.f = f;
  unsigned int u = c.u + 0x7fffu + ((c.u >> 16) & 1u);
  return (unsigned short)(u >> 16);
}

DEVI void gl_lds16(const void* g, void* l) {  // async global->LDS, 16B/lane, linear dest
  __builtin_amdgcn_global_load_lds(
      (const __attribute__((address_space(1))) unsigned int*)g,
      (__attribute__((address_space(3))) unsigned int*)l, 16, 0, 0);
}

DEVI void wg_barrier() {
  asm volatile("" ::: "memory");
  __builtin_amdgcn_s_barrier();
  asm volatile("" ::: "memory");
}

DEVI float fast_exp2(float x) {
#if __has_builtin(__builtin_amdgcn_exp2f)
  return __builtin_amdgcn_exp2f(x);
#else
  return __builtin_exp2f(x);
#endif
}

// ---------------------------------------------------------------- prep kernels
__global__ __launch_bounds__(256) void x_to_bf16_kernel(const float* __restrict__ x,
                                                        unsigned short* __restrict__ x16) {
  const long n4 = (long)MM * EE / 4;
  long i = (long)blockIdx.x * blockDim.x + threadIdx.x;
  const long stride = (long)gridDim.x * blockDim.x;
  for (; i < n4; i += stride) {
    const float4 v = ((const float4*)x)[i];
    ushort4 o;
    o.x = f2bf(v.x); o.y = f2bf(v.y); o.z = f2bf(v.z); o.w = f2bf(v.w);
    ((ushort4*)x16)[i] = o;
  }
}

// transpose+convert W [E][A] f32 -> WT [A][E] bf16; grid (E/64, A/64, 3)
__global__ __launch_bounds__(256) void wt_kernel(const float* __restrict__ Wq,
                                                 const float* __restrict__ Wk,
                                                 const float* __restrict__ Wv,
                                                 unsigned short* __restrict__ WT) {
  const float* W = (blockIdx.z == 0) ? Wq : (blockIdx.z == 1) ? Wk : Wv;
  unsigned short* out = WT + (size_t)blockIdx.z * AA * EE;
  __shared__ unsigned short t[64][65];
  const int k0 = blockIdx.x * 64, n0 = blockIdx.y * 64;
  #pragma unroll
  for (int i = 0; i < 16; ++i) {
    int idx = i * 256 + threadIdx.x;
    int r = idx >> 6, c = idx & 63;              // r: k-local, c: n-local
    t[r][c] = f2bf(W[(size_t)(k0 + r) * AA + n0 + c]);
  }
  __syncthreads();
  #pragma unroll
  for (int i = 0; i < 16; ++i) {
    int idx = i * 256 + threadIdx.x;
    int r = idx >> 6, c = idx & 63;              // r: n-local, c: k-local
    out[(size_t)(n0 + r) * EE + k0 + c] = t[c][r];
  }
}

// ---------------------------------------------------------------- QKV projection
// C[m][n] = sum_k X16[m][k]*WT[z][n][k]  (NT GEMM), 128x128 tile, BK=64,
// 4 waves (2x2 of 64x64), double-buffered global_load_lds + counted vmcnt.
__global__ __launch_bounds__(256, 2) void proj_kernel(
    const unsigned short* __restrict__ X16, const unsigned short* __restrict__ WT,
    const float* __restrict__ bq, const float* __restrict__ bk, const float* __restrict__ bv,
    unsigned short* __restrict__ Qo, unsigned short* __restrict__ Ko,
    unsigned short* __restrict__ VTo) {
  constexpr int BK = 64, NKT = EE / BK;  // 16 K-steps
  __shared__ unsigned char lds[65536];   // 2x16KB A | 2x16KB B; reused by epilogue
  unsigned char* ldsA = lds;             // [buf][128 rows][128B]
  unsigned char* ldsB = lds + 32768;
  const int tid = threadIdx.x, lane = tid & 63, wave = tid >> 6;
  const int z = blockIdx.z;
  const int m0 = blockIdx.x * 128, n0 = blockIdx.y * 128;
  const unsigned short* Wz = WT + (size_t)z * AA * EE;

  f32x4 acc[4][4];
  #pragma unroll
  for (int i = 0; i < 4; ++i)
    #pragma unroll
    for (int j = 0; j < 4; ++j) acc[i][j] = f32x4{0.f, 0.f, 0.f, 0.f};

  auto stage = [&](int buf, int kt) {
    #pragma unroll
    for (int i = 0; i < 4; ++i) {
      int c = i * 256 + tid;                 // 1024 16B chunks (A-tile)
      int row = c >> 3;
      int cb = ((c & 7) * 16) ^ ((row & 7) << 4);   // pre-swizzled source column
      gl_lds16(X16 + (size_t)(m0 + row) * EE + kt * BK + (cb >> 1), ldsA + buf * 16384 + c * 16);
    }
    #pragma unroll
    for (int i = 0; i < 4; ++i) {
      int c = i * 256 + tid;
      int row = c >> 3;
      int cb = ((c & 7) * 16) ^ ((row & 7) << 4);
      gl_lds16(Wz + (size_t)(n0 + row) * EE + kt * BK + (cb >> 1), ldsB + buf * 16384 + c * 16);
    }
  };

  auto compute = [&](int buf) {
    #pragma unroll
    for (int kk = 0; kk < 2; ++kk) {
      s16x8 a[4], b[4];
      #pragma unroll
      for (int m = 0; m < 4; ++m) {
        int row = (wave >> 1) * 64 + m * 16 + (lane & 15);
        int cb = (kk * 64 + (lane >> 4) * 16) ^ ((row & 7) << 4);
        a[m] = *(const s16x8*)(ldsA + buf * 16384 + row * 128 + cb);
      }
      #pragma unroll
      for (int n = 0; n < 4; ++n) {
        int row = (wave & 1) * 64 + n * 16 + (lane & 15);
        int cb = (kk * 64 + (lane >> 4) * 16) ^ ((row & 7) << 4);
        b[n] = *(const s16x8*)(ldsB + buf * 16384 + row * 128 + cb);
      }
      #pragma unroll
      for (int m = 0; m < 4; ++m)
        #pragma unroll
        for (int n = 0; n < 4; ++n)
          acc[m][n] = __builtin_amdgcn_mfma_f32_16x16x32_bf16(a[m], b[n], acc[m][n], 0, 0, 0);
    }
  };

  stage(0, 0);
  for (int kt = 0; kt < NKT; ++kt) {
    const int cur = kt & 1;
    if (kt + 1 < NKT) {
      stage(cur ^ 1, kt + 1);
      asm volatile("s_waitcnt vmcnt(8)" ::: "memory");  // current tile done; prefetch stays in flight
    } else {
      asm volatile("s_waitcnt vmcnt(0)" ::: "memory");
    }
    wg_barrier();
    compute(cur);
    wg_barrier();
  }

  // ---- epilogue: bias (+scale for Q), bf16, coalesce via LDS [128][136] tile ----
  const float* bias = (z == 0) ? bq : (z == 1) ? bk : bv;
  const float scale = (z == 0) ? 0.04562280215f : 1.0f;  // log2(e)/sqrt(1000) folded into Q
  unsigned short* T = (unsigned short*)lds;              // 128*136*2 = 34816B
  const int rbase = (wave >> 1) * 64 + (lane >> 4) * 4;  // local row (m / s dim)
  const int cbase = (wave & 1) * 64 + (lane & 15);       // local col (n / a dim)
  float bvals[4];
  #pragma unroll
  for (int n = 0; n < 4; ++n) bvals[n] = bias[n0 + cbase + n * 16];
  #pragma unroll
  for (int m = 0; m < 4; ++m) {
    #pragma unroll
    for (int n = 0; n < 4; ++n) {
      const int cl = cbase + n * 16;
      #pragma unroll
      for (int j = 0; j < 4; ++j) {
        const int rl = rbase + m * 16 + j;
        const unsigned short h = f2bf((acc[m][n][j] + bvals[n]) * scale);
        if (z == 2) T[cl * 136 + rl] = h;   // transposed: [a_local][s_local]
        else        T[rl * 136 + cl] = h;   // natural:    [s_local][a_local]
      }
    }
  }
  wg_barrier();
  #pragma unroll
  for (int i = 0; i < 8; ++i) {
    int c2 = i * 256 + tid;                 // 2048 chunks of 16B
    int r = c2 >> 4, ch = (c2 & 15) * 8;
    s16x8 chunk = *(const s16x8*)&T[r * 136 + ch];
    if (z == 2) {
      // r = a_local, ch.. = s_local. 16B chunk never straddles a batch (8 | 1000).
      const int rowg0 = m0 + ch;
      const int bb2 = rowg0 / SS, ss2 = rowg0 - bb2 * SS;
      *(s16x8*)&VTo[(size_t)bb2 * AA * SS + (size_t)(n0 + r) * SS + ss2] = chunk;
    } else {
      unsigned short* O = (z == 0) ? Qo : Ko;
      *(s16x8*)&O[(size_t)(m0 + r) * AA + n0 + ch] = chunk;
    }
  }
}

// ---------------------------------------------------------------- fused causal attention
// grid 256, 512 threads (8 waves), 128 q-rows/block. b = L&31 (XCD pin: L%8=b%8),
// g = 7-(L>>5). One 64KB K/V stage serves 128 q-rows (stage traffic halved vs 4-wave).
// K+V double-buffered (138KB LDS, 1 block/CU, 8 waves = 2/SIMD): stage(t+1) issued
// BEFORE compute(t), single vmcnt(0)+barrier per tile -> load latency hidden.
__global__ __launch_bounds__(512, 2) void attn_kernel(
    const unsigned short* __restrict__ Qs, const unsigned short* __restrict__ Ks,
    const unsigned short* __restrict__ VT, float* __restrict__ out) {
  constexpr int KVB = 32;
  __shared__ unsigned char ldsK[2][KVB * AA * 2];   // 2 x 32KB, XOR-swizzled rows
  __shared__ unsigned char ldsV[2][AA * KVB * 2];   // 2 x 32KB, pair-layout swizzled
  __shared__ unsigned char ldsP[8][16 * 80];        // per-wave P bounce, 10KB

  const int tid = threadIdx.x, lane = tid & 63, wave = tid >> 6;
  const int L = blockIdx.x;
  const int b = L & 31;                      // XCD = L%8 = b%8
  const int g = 7 - (L >> 5);                // q-chunk of 128 rows
  const int q0w = g * 128 + wave * 16;

  // hoisted per-lane stage offsets (elements); 4096 chunks over 512 threads
  const unsigned short* kbase = Ks + (size_t)b * SS * AA;
  const unsigned short* vbase = VT + (size_t)b * AA * SS;
  unsigned int koff[4], voff[4];
  #pragma unroll
  for (int i = 0; i < 4; ++i) {
    int c = i * 512 + tid;                   // 2048 chunks
    int r = c >> 6;                          // K row 0..31
    int cb = ((c & 63) * 16) ^ ((r & 7) << 4);
    koff[i] = r * AA + (cb >> 1);
    int pair = c >> 3;
    int within = (c & 7) * 16;
    int half = within >> 6;
    int kb = (within & 63) ^ ((pair & 3) << 4);
    int a_ = pair * 2 + half;
    voff[i] = a_ * SS + (kb >> 1);
  }

  // Q fragments in registers: 16 rows x 512 k
  s16x8 qf[16];
  {
    int qrow = q0w + (lane & 15);
    int qr = qrow < SS ? qrow : SS - 1;
    const unsigned short* qp = Qs + (size_t)(b * SS + qr) * AA + (lane >> 4) * 8;
    #pragma unroll
    for (int f = 0; f < 16; ++f) qf[f] = *(const s16x8*)(qp + f * 32);
  }

  f32x4 o[32];
  #pragma unroll
  for (int n = 0; n < 32; ++n) o[n] = f32x4{0.f, 0.f, 0.f, 0.f};
  float mrun[4], ps[4];
  #pragma unroll
  for (int j = 0; j < 4; ++j) { mrun[j] = -__builtin_inff(); ps[j] = 0.f; }

  const int kmax = (g * 128 + 128 < SS) ? g * 128 + 128 : SS;
  const int ntiles = (kmax + KVB - 1) / KVB;

  auto stageKV = [&](int buf, int t) {
    #pragma unroll
    for (int i = 0; i < 4; ++i)
      gl_lds16(kbase + koff[i] + (unsigned)(t * (KVB * AA)),
               &ldsK[buf][(i * 512 + tid) * 16]);
    #pragma unroll
    for (int i = 0; i < 4; ++i)
      gl_lds16(vbase + voff[i] + (unsigned)(t * KVB),
               &ldsV[buf][(i * 512 + tid) * 16]);
  };

  stageKV(0, 0);
  asm volatile("s_waitcnt vmcnt(0)" ::: "memory");
  wg_barrier();

  for (int t = 0; t < ntiles; ++t) {
    const int cur = t & 1;
    const int k0 = t * KVB;
    if (t + 1 < ntiles) stageKV(cur ^ 1, t + 1);   // issue prefetch BEFORE compute

    // ---- QK^T: p[16 rows x 32 keys], 4 independent 8-deep MFMA chains ----
    f32x4 p0a = {0.f, 0.f, 0.f, 0.f}, p0b = {0.f, 0.f, 0.f, 0.f};
    f32x4 p1a = {0.f, 0.f, 0.f, 0.f}, p1b = {0.f, 0.f, 0.f, 0.f};
    {
      const int r0 = lane & 15;
      const int sw = (r0 & 7) << 4;
      const int kb16 = (lane >> 4) * 16;
      const int rb0 = r0 << 10, rb1 = (r0 + 16) << 10;
      #pragma unroll
      for (int f = 0; f < 8; ++f) {
        const int offA = f * 64 + kb16;
        const int offB = (f + 8) * 64 + kb16;
        s16x8 k0A = *(const s16x8*)&ldsK[cur][rb0 + (offA ^ sw)];
        s16x8 k1A = *(const s16x8*)&ldsK[cur][rb1 + (offA ^ sw)];
        s16x8 k0B = *(const s16x8*)&ldsK[cur][rb0 + (offB ^ sw)];
        s16x8 k1B = *(const s16x8*)&ldsK[cur][rb1 + (offB ^ sw)];
        p0a = __builtin_amdgcn_mfma_f32_16x16x32_bf16(qf[f], k0A, p0a, 0, 0, 0);
        p1a = __builtin_amdgcn_mfma_f32_16x16x32_bf16(qf[f], k1A, p1a, 0, 0, 0);
        p0b = __builtin_amdgcn_mfma_f32_16x16x32_bf16(qf[f + 8], k0B, p0b, 0, 0, 0);
        p1b = __builtin_amdgcn_mfma_f32_16x16x32_bf16(qf[f + 8], k1B, p1b, 0, 0, 0);
      }
    }
    f32x4 p0 = p0a + p0b, p1 = p1a + p1b;

    // ---- causal mask + defer-max online softmax ----
    const int kcol = k0 + (lane & 15);
    float lm[4];
    #pragma unroll
    for (int j = 0; j < 4; ++j) {
      const int q = q0w + (lane >> 4) * 4 + j;
      float s0 = p0[j], s1 = p1[j];
      if (kcol > q || kcol >= SS) s0 = -__builtin_inff();
      if (kcol + 16 > q || kcol + 16 >= SS) s1 = -__builtin_inff();
      p0[j] = s0; p1[j] = s1;
      lm[j] = fmaxf(s0, s1);
    }
    const int myneed = (lm[0] > mrun[0] + 8.f) | (lm[1] > mrun[1] + 8.f) |
                       (lm[2] > mrun[2] + 8.f) | (lm[3] > mrun[3] + 8.f);
    if (__any(myneed)) {                        // rare after tile 0
      float rm[4] = {lm[0], lm[1], lm[2], lm[3]};
      #pragma unroll
      for (int st = 1; st <= 8; st <<= 1)
        #pragma unroll
        for (int j = 0; j < 4; ++j) rm[j] = fmaxf(rm[j], __shfl_xor(rm[j], st));
      float corr[4];
      #pragma unroll
      for (int j = 0; j < 4; ++j) {
        const float mnew = fmaxf(mrun[j], rm[j]);
        corr[j] = fast_exp2(mrun[j] - mnew);    // exp2(-inf)=0 on first tile
        mrun[j] = mnew;
        ps[j] *= corr[j];
      }
      #pragma unroll
      for (int n = 0; n < 32; ++n)
        #pragma unroll
        for (int j = 0; j < 4; ++j) o[n][j] *= corr[j];
    }
    #pragma unroll
    for (int j = 0; j < 4; ++j) {               // P = exp2(s - m); per-lane partial sums
      const float e0 = fast_exp2(p0[j] - mrun[j]);
      const float e1 = fast_exp2(p1[j] - mrun[j]);
      ps[j] += e0 + e1;
      p0[j] = e0; p1[j] = e1;
    }

    // ---- P (C-layout) -> bf16 -> wave-private LDS -> A-fragment ----
    {
      unsigned short* pb = (unsigned short*)&ldsP[wave][0];
      const int prow = (lane >> 4) * 4, pc = lane & 15;
      #pragma unroll
      for (int j = 0; j < 4; ++j) {
        pb[(prow + j) * 40 + pc]      = f2bf(p0[j]);
        pb[(prow + j) * 40 + pc + 16] = f2bf(p1[j]);
      }
    }
    s16x8 pa;
    {
      const unsigned char* pp = &ldsP[wave][(lane & 15) * 80 + (lane >> 4) * 16];
      s16x4 lo = *(const s16x4*)pp;
      s16x4 hi = *(const s16x4*)(pp + 8);
      pa = s16x8{lo[0], lo[1], lo[2], lo[3], hi[0], hi[1], hi[2], hi[3]};
    }

    // ---- PV: o[q][a] += P[q][k] * VT[a][k] ----
    #pragma unroll
    for (int n = 0; n < 32; ++n) {
      const int a_ = n * 16 + (lane & 15);
      const int pair = a_ >> 1;
      const int off = pair * 128 + (a_ & 1) * 64 + (((lane >> 4) * 16) ^ ((pair & 3) << 4));
      s16x8 vb = *(const s16x8*)&ldsV[cur][off];
      o[n] = __builtin_amdgcn_mfma_f32_16x16x32_bf16(pa, vb, o[n], 0, 0, 0);
    }

    asm volatile("s_waitcnt vmcnt(0)" ::: "memory");  // prefetch landed (covered by compute)
    wg_barrier();                                     // tile cur fully consumed by all waves
  }

  // ---- finalize: reduce per-lane partial sums, divide, store fp32 ----
  #pragma unroll
  for (int st = 1; st <= 8; st <<= 1)
    #pragma unroll
    for (int j = 0; j < 4; ++j) ps[j] += __shfl_xor(ps[j], st);
  #pragma unroll
  for (int j = 0; j < 4; ++j) {
    const int q = q0w + (lane >> 4) * 4 + j;
    if (q < SS) {
      const float inv = 1.0f / ps[j];
      float* op = out + (size_t)(b * SS + q) * AA + (lane & 15);
      #pragma unroll
      for (int n = 0; n < 32; ++n) op[n * 16] = o[n][j] * inv;
    }
  }
}

// ---------------------------------------------------------------- launch
extern "C" void kernel_launch(void* const* d_in, const int* in_sizes, int n_in,
                              void* d_out, int out_size, void* d_ws, size_t ws_size,
                              hipStream_t stream) {
  const float* x  = (const float*)d_in[0];
  const float* Wk = (const float*)d_in[1];
  const float* bk = (const float*)d_in[2];
  const float* Wq = (const float*)d_in[3];
  const float* bq = (const float*)d_in[4];
  const float* Wv = (const float*)d_in[5];
  const float* bv = (const float*)d_in[6];

  char* ws = (char*)d_ws;
  unsigned short* X16 = (unsigned short*)(ws + OFF_X16);
  unsigned short* Qw  = (unsigned short*)(ws + OFF_Q);
  unsigned short* Kw  = (unsigned short*)(ws + OFF_K);
  unsigned short* VTw = (unsigned short*)(ws + OFF_VT);
  unsigned short* WT  = (unsigned short*)(ws + OFF_WT);

  x_to_bf16_kernel<<<dim3(2048), dim3(256), 0, stream>>>(x, X16);
  wt_kernel<<<dim3(EE / 64, AA / 64, 3), dim3(256), 0, stream>>>(Wq, Wk, Wv, WT);
  proj_kernel<<<dim3(MM / 128, AA / 128, 3), dim3(256), 0, stream>>>(
      X16, WT, bq, bk, bv, Qw, Kw, VTw);
  attn_kernel<<<dim3(256), dim3(512), 0, stream>>>(Qw, Kw, VTw, (float*)d_out);
}

// Round 11
// 317.860 us; speedup vs baseline: 1.7316x; 1.0516x over previous
//
#include <hip/hip_runtime.h>
#include <hip/hip_bf16.h>
#include <stdint.h>

#define DEVI __device__ __forceinline__

typedef short s16x8 __attribute__((ext_vector_type(8)));
typedef short s16x4 __attribute__((ext_vector_type(4)));
typedef float f32x4 __attribute__((ext_vector_type(4)));

static constexpr int BB = 32, SS = 1000, EE = 1024, AA = 512;
static constexpr int MM = BB * SS;  // 32000

// workspace layout (bytes)
static constexpr size_t OFF_X16 = 0;                                   // [M][E] bf16
static constexpr size_t OFF_Q   = OFF_X16 + (size_t)MM * EE * 2;       // [M][A] bf16 (pre-scaled by log2e/sqrt(S))
static constexpr size_t OFF_K   = OFF_Q  + (size_t)MM * AA * 2;        // [M][A] bf16
static constexpr size_t OFF_VT  = OFF_K  + (size_t)MM * AA * 2;       // [B][A][S] bf16
static constexpr size_t OFF_WT  = OFF_VT + (size_t)BB * AA * SS * 2;   // 3 x [A][E] bf16 (z=0:Wq 1:Wk 2:Wv)

DEVI unsigned short f2bf(float f) {  // round-to-nearest-even f32 -> bf16
  union { float f; unsigned int u; } c; c.f = f;
  unsigned int u = c.u + 0x7fffu + ((c.u >> 16) & 1u);
  return (unsigned short)(u >> 16);
}

DEVI void gl_lds16(const void* g, void* l) {  // async global->LDS, 16B/lane, linear dest
  __builtin_amdgcn_global_load_lds(
      (const __attribute__((address_space(1))) unsigned int*)g,
      (__attribute__((address_space(3))) unsigned int*)l, 16, 0, 0);
}

DEVI void wg_barrier() {
  asm volatile("" ::: "memory");
  __builtin_amdgcn_s_barrier();
  asm volatile("" ::: "memory");
}

DEVI float fast_exp2(float x) {
#if __has_builtin(__builtin_amdgcn_exp2f)
  return __builtin_amdgcn_exp2f(x);
#else
  return __builtin_exp2f(x);
#endif
}

// ---------------------------------------------------------------- prep kernels
__global__ __launch_bounds__(256) void x_to_bf16_kernel(const float* __restrict__ x,
                                                        unsigned short* __restrict__ x16) {
  const long n4 = (long)MM * EE / 4;
  long i = (long)blockIdx.x * blockDim.x + threadIdx.x;
  const long stride = (long)gridDim.x * blockDim.x;
  for (; i < n4; i += stride) {
    const float4 v = ((const float4*)x)[i];
    ushort4 o;
    o.x = f2bf(v.x); o.y = f2bf(v.y); o.z = f2bf(v.z); o.w = f2bf(v.w);
    ((ushort4*)x16)[i] = o;
  }
}

// transpose+convert W [E][A] f32 -> WT [A][E] bf16; grid (E/64, A/64, 3)
__global__ __launch_bounds__(256) void wt_kernel(const float* __restrict__ Wq,
                                                 const float* __restrict__ Wk,
                                                 const float* __restrict__ Wv,
                                                 unsigned short* __restrict__ WT) {
  const float* W = (blockIdx.z == 0) ? Wq : (blockIdx.z == 1) ? Wk : Wv;
  unsigned short* out = WT + (size_t)blockIdx.z * AA * EE;
  __shared__ unsigned short t[64][65];
  const int k0 = blockIdx.x * 64, n0 = blockIdx.y * 64;
  #pragma unroll
  for (int i = 0; i < 16; ++i) {
    int idx = i * 256 + threadIdx.x;
    int r = idx >> 6, c = idx & 63;              // r: k-local, c: n-local
    t[r][c] = f2bf(W[(size_t)(k0 + r) * AA + n0 + c]);
  }
  __syncthreads();
  #pragma unroll
  for (int i = 0; i < 16; ++i) {
    int idx = i * 256 + threadIdx.x;
    int r = idx >> 6, c = idx & 63;              // r: n-local, c: k-local
    out[(size_t)(n0 + r) * EE + k0 + c] = t[c][r];
  }
}

// ---------------------------------------------------------------- QKV projection
// C[m][n] = sum_k X16[m][k]*WT[z][n][k]  (NT GEMM), 128x128 tile, BK=64,
// 4 waves (2x2 of 64x64), double-buffered global_load_lds + counted vmcnt.
// Grid: 1D, 3000 blocks, (n,z) INNERMOST: the 12 blocks sharing an X m-panel
// dispatch consecutively -> X panel fetched once per L2, L3-served across XCDs.
__global__ __launch_bounds__(256, 2) void proj_kernel(
    const unsigned short* __restrict__ X16, const unsigned short* __restrict__ WT,
    const float* __restrict__ bq, const float* __restrict__ bk, const float* __restrict__ bv,
    unsigned short* __restrict__ Qo, unsigned short* __restrict__ Ko,
    unsigned short* __restrict__ VTo) {
  constexpr int BK = 64, NKT = EE / BK;  // 16 K-steps
  __shared__ unsigned char lds[65536];   // 2x16KB A | 2x16KB B; reused by epilogue
  unsigned char* ldsA = lds;             // [buf][128 rows][128B]
  unsigned char* ldsB = lds + 32768;
  const int tid = threadIdx.x, lane = tid & 63, wave = tid >> 6;
  const int id = blockIdx.x;
  const int r12 = id % 12;
  const int z = r12 >> 2;                 // 0:Wq 1:Wk 2:Wv
  const int m0 = (id / 12) * 128, n0 = (r12 & 3) * 128;
  const unsigned short* Wz = WT + (size_t)z * AA * EE;

  f32x4 acc[4][4];
  #pragma unroll
  for (int i = 0; i < 4; ++i)
    #pragma unroll
    for (int j = 0; j < 4; ++j) acc[i][j] = f32x4{0.f, 0.f, 0.f, 0.f};

  auto stage = [&](int buf, int kt) {
    #pragma unroll
    for (int i = 0; i < 4; ++i) {
      int c = i * 256 + tid;                 // 1024 16B chunks (A-tile)
      int row = c >> 3;
      int cb = ((c & 7) * 16) ^ ((row & 7) << 4);   // pre-swizzled source column
      gl_lds16(X16 + (size_t)(m0 + row) * EE + kt * BK + (cb >> 1), ldsA + buf * 16384 + c * 16);
    }
    #pragma unroll
    for (int i = 0; i < 4; ++i) {
      int c = i * 256 + tid;
      int row = c >> 3;
      int cb = ((c & 7) * 16) ^ ((row & 7) << 4);
      gl_lds16(Wz + (size_t)(n0 + row) * EE + kt * BK + (cb >> 1), ldsB + buf * 16384 + c * 16);
    }
  };

  auto compute = [&](int buf) {
    #pragma unroll
    for (int kk = 0; kk < 2; ++kk) {
      s16x8 a[4], b[4];
      #pragma unroll
      for (int m = 0; m < 4; ++m) {
        int row = (wave >> 1) * 64 + m * 16 + (lane & 15);
        int cb = (kk * 64 + (lane >> 4) * 16) ^ ((row & 7) << 4);
        a[m] = *(const s16x8*)(ldsA + buf * 16384 + row * 128 + cb);
      }
      #pragma unroll
      for (int n = 0; n < 4; ++n) {
        int row = (wave & 1) * 64 + n * 16 + (lane & 15);
        int cb = (kk * 64 + (lane >> 4) * 16) ^ ((row & 7) << 4);
        b[n] = *(const s16x8*)(ldsB + buf * 16384 + row * 128 + cb);
      }
      #pragma unroll
      for (int m = 0; m < 4; ++m)
        #pragma unroll
        for (int n = 0; n < 4; ++n)
          acc[m][n] = __builtin_amdgcn_mfma_f32_16x16x32_bf16(a[m], b[n], acc[m][n], 0, 0, 0);
    }
  };

  stage(0, 0);
  for (int kt = 0; kt < NKT; ++kt) {
    const int cur = kt & 1;
    if (kt + 1 < NKT) {
      stage(cur ^ 1, kt + 1);
      asm volatile("s_waitcnt vmcnt(8)" ::: "memory");  // current tile done; prefetch stays in flight
    } else {
      asm volatile("s_waitcnt vmcnt(0)" ::: "memory");
    }
    wg_barrier();
    compute(cur);
    wg_barrier();
  }

  // ---- epilogue: bias (+scale for Q), bf16, coalesce via LDS [128][136] tile ----
  const float* bias = (z == 0) ? bq : (z == 1) ? bk : bv;
  const float scale = (z == 0) ? 0.04562280215f : 1.0f;  // log2(e)/sqrt(1000) folded into Q
  unsigned short* T = (unsigned short*)lds;              // 128*136*2 = 34816B
  const int rbase = (wave >> 1) * 64 + (lane >> 4) * 4;  // local row (m / s dim)
  const int cbase = (wave & 1) * 64 + (lane & 15);       // local col (n / a dim)
  float bvals[4];
  #pragma unroll
  for (int n = 0; n < 4; ++n) bvals[n] = bias[n0 + cbase + n * 16];
  #pragma unroll
  for (int m = 0; m < 4; ++m) {
    #pragma unroll
    for (int n = 0; n < 4; ++n) {
      const int cl = cbase + n * 16;
      #pragma unroll
      for (int j = 0; j < 4; ++j) {
        const int rl = rbase + m * 16 + j;
        const unsigned short h = f2bf((acc[m][n][j] + bvals[n]) * scale);
        if (z == 2) T[cl * 136 + rl] = h;   // transposed: [a_local][s_local]
        else        T[rl * 136 + cl] = h;   // natural:    [s_local][a_local]
      }
    }
  }
  wg_barrier();
  #pragma unroll
  for (int i = 0; i < 8; ++i) {
    int c2 = i * 256 + tid;                 // 2048 chunks of 16B
    int r = c2 >> 4, ch = (c2 & 15) * 8;
    s16x8 chunk = *(const s16x8*)&T[r * 136 + ch];
    if (z == 2) {
      // r = a_local, ch.. = s_local. 16B chunk never straddles a batch (8 | 1000).
      const int rowg0 = m0 + ch;
      const int bb2 = rowg0 / SS, ss2 = rowg0 - bb2 * SS;
      *(s16x8*)&VTo[(size_t)bb2 * AA * SS + (size_t)(n0 + r) * SS + ss2] = chunk;
    } else {
      unsigned short* O = (z == 0) ? Qo : Ko;
      *(s16x8*)&O[(size_t)(m0 + r) * AA + n0 + ch] = chunk;
    }
  }
}

// ---------------------------------------------------------------- fused causal attention
// grid 256, 512 threads (8 waves), 128 q-rows/block. b = L&31 (XCD pin: L%8=b%8),
// g = 7-(L>>5). One 64KB K/V stage serves 128 q-rows (stage traffic halved vs 4-wave).
// K+V double-buffered (138KB LDS, 1 block/CU, 8 waves = 2/SIMD): stage(t+1) issued
// BEFORE compute(t), single vmcnt(0)+barrier per tile -> load latency hidden.
__global__ __launch_bounds__(512, 2) void attn_kernel(
    const unsigned short* __restrict__ Qs, const unsigned short* __restrict__ Ks,
    const unsigned short* __restrict__ VT, float* __restrict__ out) {
  constexpr int KVB = 32;
  __shared__ unsigned char ldsK[2][KVB * AA * 2];   // 2 x 32KB, XOR-swizzled rows
  __shared__ unsigned char ldsV[2][AA * KVB * 2];   // 2 x 32KB, pair-layout swizzled
  __shared__ unsigned char ldsP[8][16 * 80];        // per-wave P bounce, 10KB

  const int tid = threadIdx.x, lane = tid & 63, wave = tid >> 6;
  const int L = blockIdx.x;
  const int b = L & 31;                      // XCD = L%8 = b%8
  const int g = 7 - (L >> 5);                // q-chunk of 128 rows
  const int q0w = g * 128 + wave * 16;

  // hoisted per-lane stage offsets (elements); 4096 chunks over 512 threads
  const unsigned short* kbase = Ks + (size_t)b * SS * AA;
  const unsigned short* vbase = VT + (size_t)b * AA * SS;
  unsigned int koff[4], voff[4];
  #pragma unroll
  for (int i = 0; i < 4; ++i) {
    int c = i * 512 + tid;                   // 2048 chunks
    int r = c >> 6;                          // K row 0..31
    int cb = ((c & 63) * 16) ^ ((r & 7) << 4);
    koff[i] = r * AA + (cb >> 1);
    int pair = c >> 3;
    int within = (c & 7) * 16;
    int half = within >> 6;
    int kb = (within & 63) ^ ((pair & 3) << 4);
    int a_ = pair * 2 + half;
    voff[i] = a_ * SS + (kb >> 1);
  }

  // Q fragments in registers: 16 rows x 512 k
  s16x8 qf[16];
  {
    int qrow = q0w + (lane & 15);
    int qr = qrow < SS ? qrow : SS - 1;
    const unsigned short* qp = Qs + (size_t)(b * SS + qr) * AA + (lane >> 4) * 8;
    #pragma unroll
    for (int f = 0; f < 16; ++f) qf[f] = *(const s16x8*)(qp + f * 32);
  }

  f32x4 o[32];
  #pragma unroll
  for (int n = 0; n < 32; ++n) o[n] = f32x4{0.f, 0.f, 0.f, 0.f};
  float mrun[4], ps[4];
  #pragma unroll
  for (int j = 0; j < 4; ++j) { mrun[j] = -__builtin_inff(); ps[j] = 0.f; }

  const int kmax = (g * 128 + 128 < SS) ? g * 128 + 128 : SS;
  const int ntiles = (kmax + KVB - 1) / KVB;

  auto stageKV = [&](int buf, int t) {
    #pragma unroll
    for (int i = 0; i < 4; ++i)
      gl_lds16(kbase + koff[i] + (unsigned)(t * (KVB * AA)),
               &ldsK[buf][(i * 512 + tid) * 16]);
    #pragma unroll
    for (int i = 0; i < 4; ++i)
      gl_lds16(vbase + voff[i] + (unsigned)(t * KVB),
               &ldsV[buf][(i * 512 + tid) * 16]);
  };

  stageKV(0, 0);
  asm volatile("s_waitcnt vmcnt(0)" ::: "memory");
  wg_barrier();

  for (int t = 0; t < ntiles; ++t) {
    const int cur = t & 1;
    const int k0 = t * KVB;
    if (t + 1 < ntiles) stageKV(cur ^ 1, t + 1);   // issue prefetch BEFORE compute

    // ---- QK^T: p[16 rows x 32 keys], 4 independent 8-deep MFMA chains ----
    f32x4 p0a = {0.f, 0.f, 0.f, 0.f}, p0b = {0.f, 0.f, 0.f, 0.f};
    f32x4 p1a = {0.f, 0.f, 0.f, 0.f}, p1b = {0.f, 0.f, 0.f, 0.f};
    {
      const int r0 = lane & 15;
      const int sw = (r0 & 7) << 4;
      const int kb16 = (lane >> 4) * 16;
      const int rb0 = r0 << 10, rb1 = (r0 + 16) << 10;
      #pragma unroll
      for (int f = 0; f < 8; ++f) {
        const int offA = f * 64 + kb16;
        const int offB = (f + 8) * 64 + kb16;
        s16x8 k0A = *(const s16x8*)&ldsK[cur][rb0 + (offA ^ sw)];
        s16x8 k1A = *(const s16x8*)&ldsK[cur][rb1 + (offA ^ sw)];
        s16x8 k0B = *(const s16x8*)&ldsK[cur][rb0 + (offB ^ sw)];
        s16x8 k1B = *(const s16x8*)&ldsK[cur][rb1 + (offB ^ sw)];
        p0a = __builtin_amdgcn_mfma_f32_16x16x32_bf16(qf[f], k0A, p0a, 0, 0, 0);
        p1a = __builtin_amdgcn_mfma_f32_16x16x32_bf16(qf[f], k1A, p1a, 0, 0, 0);
        p0b = __builtin_amdgcn_mfma_f32_16x16x32_bf16(qf[f + 8], k0B, p0b, 0, 0, 0);
        p1b = __builtin_amdgcn_mfma_f32_16x16x32_bf16(qf[f + 8], k1B, p1b, 0, 0, 0);
      }
    }
    f32x4 p0 = p0a + p0b, p1 = p1a + p1b;

    // ---- causal mask + defer-max online softmax ----
    const int kcol = k0 + (lane & 15);
    float lm[4];
    #pragma unroll
    for (int j = 0; j < 4; ++j) {
      const int q = q0w + (lane >> 4) * 4 + j;
      float s0 = p0[j], s1 = p1[j];
      if (kcol > q || kcol >= SS) s0 = -__builtin_inff();
      if (kcol + 16 > q || kcol + 16 >= SS) s1 = -__builtin_inff();
      p0[j] = s0; p1[j] = s1;
      lm[j] = fmaxf(s0, s1);
    }
    const int myneed = (lm[0] > mrun[0] + 8.f) | (lm[1] > mrun[1] + 8.f) |
                       (lm[2] > mrun[2] + 8.f) | (lm[3] > mrun[3] + 8.f);
    if (__any(myneed)) {                        // rare after tile 0
      float rm[4] = {lm[0], lm[1], lm[2], lm[3]};
      #pragma unroll
      for (int st = 1; st <= 8; st <<= 1)
        #pragma unroll
        for (int j = 0; j < 4; ++j) rm[j] = fmaxf(rm[j], __shfl_xor(rm[j], st));
      float corr[4];
      #pragma unroll
      for (int j = 0; j < 4; ++j) {
        const float mnew = fmaxf(mrun[j], rm[j]);
        corr[j] = fast_exp2(mrun[j] - mnew);    // exp2(-inf)=0 on first tile
        mrun[j] = mnew;
        ps[j] *= corr[j];
      }
      #pragma unroll
      for (int n = 0; n < 32; ++n)
        #pragma unroll
        for (int j = 0; j < 4; ++j) o[n][j] *= corr[j];
    }
    #pragma unroll
    for (int j = 0; j < 4; ++j) {               // P = exp2(s - m); per-lane partial sums
      const float e0 = fast_exp2(p0[j] - mrun[j]);
      const float e1 = fast_exp2(p1[j] - mrun[j]);
      ps[j] += e0 + e1;
      p0[j] = e0; p1[j] = e1;
    }

    // ---- P (C-layout) -> bf16 -> wave-private LDS -> A-fragment ----
    {
      unsigned short* pb = (unsigned short*)&ldsP[wave][0];
      const int prow = (lane >> 4) * 4, pc = lane & 15;
      #pragma unroll
      for (int j = 0; j < 4; ++j) {
        pb[(prow + j) * 40 + pc]      = f2bf(p0[j]);
        pb[(prow + j) * 40 + pc + 16] = f2bf(p1[j]);
      }
    }
    s16x8 pa;
    {
      const unsigned char* pp = &ldsP[wave][(lane & 15) * 80 + (lane >> 4) * 16];
      s16x4 lo = *(const s16x4*)pp;
      s16x4 hi = *(const s16x4*)(pp + 8);
      pa = s16x8{lo[0], lo[1], lo[2], lo[3], hi[0], hi[1], hi[2], hi[3]};
    }

    // ---- PV: o[q][a] += P[q][k] * VT[a][k] ----
    #pragma unroll
    for (int n = 0; n < 32; ++n) {
      const int a_ = n * 16 + (lane & 15);
      const int pair = a_ >> 1;
      const int off = pair * 128 + (a_ & 1) * 64 + (((lane >> 4) * 16) ^ ((pair & 3) << 4));
      s16x8 vb = *(const s16x8*)&ldsV[cur][off];
      o[n] = __builtin_amdgcn_mfma_f32_16x16x32_bf16(pa, vb, o[n], 0, 0, 0);
    }

    asm volatile("s_waitcnt vmcnt(0)" ::: "memory");  // prefetch landed (covered by compute)
    wg_barrier();                                     // tile cur fully consumed by all waves
  }

  // ---- finalize: reduce per-lane partial sums, divide, store fp32 ----
  #pragma unroll
  for (int st = 1; st <= 8; st <<= 1)
    #pragma unroll
    for (int j = 0; j < 4; ++j) ps[j] += __shfl_xor(ps[j], st);
  #pragma unroll
  for (int j = 0; j < 4; ++j) {
    const int q = q0w + (lane >> 4) * 4 + j;
    if (q < SS) {
      const float inv = 1.0f / ps[j];
      float* op = out + (size_t)(b * SS + q) * AA + (lane & 15);
      #pragma unroll
      for (int n = 0; n < 32; ++n) op[n * 16] = o[n][j] * inv;
    }
  }
}

// ---------------------------------------------------------------- launch
extern "C" void kernel_launch(void* const* d_in, const int* in_sizes, int n_in,
                              void* d_out, int out_size, void* d_ws, size_t ws_size,
                              hipStream_t stream) {
  const float* x  = (const float*)d_in[0];
  const float* Wk = (const float*)d_in[1];
  const float* bk = (const float*)d_in[2];
  const float* Wq = (const float*)d_in[3];
  const float* bq = (const float*)d_in[4];
  const float* Wv = (const float*)d_in[5];
  const float* bv = (const float*)d_in[6];

  char* ws = (char*)d_ws;
  unsigned short* X16 = (unsigned short*)(ws + OFF_X16);
  unsigned short* Qw  = (unsigned short*)(ws + OFF_Q);
  unsigned short* Kw  = (unsigned short*)(ws + OFF_K);
  unsigned short* VTw = (unsigned short*)(ws + OFF_VT);
  unsigned short* WT  = (unsigned short*)(ws + OFF_WT);

  x_to_bf16_kernel<<<dim3(2048), dim3(256), 0, stream>>>(x, X16);
  wt_kernel<<<dim3(EE / 64, AA / 64, 3), dim3(256), 0, stream>>>(Wq, Wk, Wv, WT);
  proj_kernel<<<dim3(3000), dim3(256), 0, stream>>>(
      X16, WT, bq, bk, bv, Qw, Kw, VTw);
  attn_kernel<<<dim3(256), dim3(512), 0, stream>>>(Qw, Kw, VTw, (float*)d_out);
}